// Round 9
// baseline (4496.762 us; speedup 1.0000x reference)
//
#include <hip/hip_runtime.h>
#include <cstdint>

#define B_ROWS 65536
#define D_IN   640
#define D_LAT  2560
#define K_SEL  32
#define EPL    40   // 2560/64 elements per lane in wave topk
#define NKT    40   // 640/16
// OpenBLAS SKYLAKEX hypothesis: GEMM_Q=192 -> K=640 splits 192+192+128+128
#define KT_S1  12   // k 0..191
#define KT_S2  24   // k 192..383
#define KT_S3  32   // k 384..511 ; then 512..639

// ---------------- W_dec transpose: [640][2560] -> WdT [2560][640] ----------------
__global__ __launch_bounds__(256) void transpose_wdec(const float* __restrict__ Wd,
                                                      float* __restrict__ WdT) {
    __shared__ float t[32][33];
    const int j0 = blockIdx.x * 32;
    const int i0 = blockIdx.y * 32;
    const int tx = threadIdx.x & 31, ty = threadIdx.x >> 5;
#pragma unroll
    for (int q = 0; q < 4; ++q)
        t[ty + 8 * q][tx] = Wd[(size_t)(i0 + ty + 8 * q) * D_LAT + j0 + tx];
    __syncthreads();
#pragma unroll
    for (int q = 0; q < 4; ++q)
        WdT[(size_t)(j0 + ty + 8 * q) * D_IN + i0 + tx] = t[tx][ty + 8 * q];
}

// ---------------- Encoder GEMM: 4 K-panels (192,192,128,128), FMA, seq in panel --
#define BM 128
#define BN 128
#define BK 16

__global__ __launch_bounds__(256) void enc_gemm(const float* __restrict__ A,
                                                const float* __restrict__ Wb,
                                                const float* __restrict__ bias,
                                                float* __restrict__ C) {
    __shared__ float As[BK][BM + 4];
    __shared__ float Bs[BK][BN + 4];
    const int tid = threadIdx.x;
    const int n0 = blockIdx.x * BN;
    const int m0 = blockIdx.y * BM;
    const int kq = tid & 3, lr = tid >> 2;
    const float* Ap = A  + (size_t)(m0 + lr) * D_IN + kq * 4;
    const float* Bp = Wb + (size_t)(n0 + lr) * D_IN + kq * 4;

    float4 ra0 = *(const float4*)(Ap);
    float4 ra1 = *(const float4*)(Ap + (size_t)64 * D_IN);
    float4 rb0 = *(const float4*)(Bp);
    float4 rb1 = *(const float4*)(Bp + (size_t)64 * D_IN);

    const int tx = tid & 15, ty = tid >> 4;
    float accA[8][8], accB[8][8], accC[8][8], accD[8][8];
#pragma unroll
    for (int i = 0; i < 8; ++i)
#pragma unroll
        for (int j = 0; j < 8; ++j) {
            accA[i][j] = 0.f; accB[i][j] = 0.f; accC[i][j] = 0.f; accD[i][j] = 0.f;
        }

#define GEMM_STEP(ACC)                                                          \
    {                                                                           \
        __syncthreads();                                                        \
        _Pragma("unroll")                                                       \
        for (int j = 0; j < 4; ++j) {                                           \
            As[kq * 4 + j][lr]      = ((const float*)&ra0)[j];                  \
            As[kq * 4 + j][lr + 64] = ((const float*)&ra1)[j];                  \
            Bs[kq * 4 + j][lr]      = ((const float*)&rb0)[j];                  \
            Bs[kq * 4 + j][lr + 64] = ((const float*)&rb1)[j];                  \
        }                                                                       \
        __syncthreads();                                                        \
        if (kt + 1 < NKT) {                                                     \
            const float* Ap2 = Ap + (kt + 1) * BK;                              \
            const float* Bp2 = Bp + (kt + 1) * BK;                              \
            ra0 = *(const float4*)(Ap2);                                        \
            ra1 = *(const float4*)(Ap2 + (size_t)64 * D_IN);                    \
            rb0 = *(const float4*)(Bp2);                                        \
            rb1 = *(const float4*)(Bp2 + (size_t)64 * D_IN);                    \
        }                                                                       \
        _Pragma("unroll")                                                       \
        for (int k = 0; k < BK; ++k) {                                          \
            float4 a0 = *(const float4*)&As[k][ty * 4];                         \
            float4 a1 = *(const float4*)&As[k][64 + ty * 4];                    \
            float4 b0 = *(const float4*)&Bs[k][tx * 4];                         \
            float4 b1 = *(const float4*)&Bs[k][64 + tx * 4];                    \
            float av[8] = {a0.x, a0.y, a0.z, a0.w, a1.x, a1.y, a1.z, a1.w};     \
            float bv[8] = {b0.x, b0.y, b0.z, b0.w, b1.x, b1.y, b1.z, b1.w};     \
            _Pragma("unroll")                                                   \
            for (int i = 0; i < 8; ++i)                                         \
                _Pragma("unroll")                                               \
                for (int j = 0; j < 8; ++j)                                     \
                    ACC[i][j] = fmaf(av[i], bv[j], ACC[i][j]);                  \
        }                                                                       \
    }

    for (int kt = 0; kt < KT_S1; ++kt)     GEMM_STEP(accA);   // k = 0..191
    for (int kt = KT_S1; kt < KT_S2; ++kt) GEMM_STEP(accB);   // k = 192..383
    for (int kt = KT_S2; kt < KT_S3; ++kt) GEMM_STEP(accC);   // k = 384..511
    for (int kt = KT_S3; kt < NKT; ++kt)   GEMM_STEP(accD);   // k = 512..639
#undef GEMM_STEP

    float4 bias0 = *(const float4*)&bias[n0 + tx * 4];
    float4 bias1 = *(const float4*)&bias[n0 + 64 + tx * 4];
    float bb[8] = {bias0.x, bias0.y, bias0.z, bias0.w, bias1.x, bias1.y, bias1.z, bias1.w};
#pragma unroll
    for (int i = 0; i < 8; ++i) {
        const int mi = ty * 4 + (i & 3) + (i >> 2) * 64;
        float o[8];
#pragma unroll
        for (int j = 0; j < 8; ++j)
            o[j] = ((((accA[i][j] + accB[i][j]) + accC[i][j]) + accD[i][j])) + bb[j];
        *(float4*)&C[(size_t)(m0 + mi) * D_LAT + n0 + tx * 4]      = *(float4*)&o[0];
        *(float4*)&C[(size_t)(m0 + mi) * D_LAT + n0 + 64 + tx * 4] = *(float4*)&o[4];
    }
}

// ---------------- Exact top-32 per row, ties -> LOWER index ----------------------
__global__ __launch_bounds__(256) void topk32(float* __restrict__ lat,
                                              float* __restrict__ vals,
                                              int* __restrict__ idxs) {
    const int wv = threadIdx.x >> 6, lane = threadIdx.x & 63;
    const int r = blockIdx.x * 4 + wv;
    float* row = lat + (size_t)r * D_LAT;

    float v[EPL];
#pragma unroll
    for (int e = 0; e < EPL; ++e) v[e] = row[e * 64 + lane];

    const float NEGINF = -__builtin_inff();
    uint64_t mask = 0;
    float lm = NEGINF; int li = 0x7fffffff;
#pragma unroll
    for (int e = 0; e < EPL; ++e)
        if (v[e] > lm) { lm = v[e]; li = e * 64 + lane; }

    for (int t = 0; t < K_SEL; ++t) {
        float bv = lm; int bi = li;
#pragma unroll
        for (int off = 1; off < 64; off <<= 1) {
            float ov = __shfl_xor(bv, off);
            int   oi = __shfl_xor(bi, off);
            if (ov > bv || (ov == bv && oi < bi)) { bv = ov; bi = oi; }
        }
        if (lane == 0) {
            vals[(size_t)r * K_SEL + t] = bv;
            idxs[(size_t)r * K_SEL + t] = bi;
        }
        if (li == bi) {
            mask |= 1ull << (bi >> 6);
            lm = NEGINF; li = 0x7fffffff;
#pragma unroll
            for (int e = 0; e < EPL; ++e)
                if (!((mask >> e) & 1) && v[e] > lm) { lm = v[e]; li = e * 64 + lane; }
        }
    }
#pragma unroll
    for (int e = 0; e < EPL; ++e)
        row[e * 64 + lane] = ((mask >> e) & 1) ? v[e] : 0.0f;
}

// ---------------- Decoder: recon[r] = sum_k vals[r][k] * WdT[idx[r][k]][:] + b_dec
__global__ __launch_bounds__(256) void dec_kernel(const float* __restrict__ vals,
                                                  const int* __restrict__ idxs,
                                                  const float* __restrict__ WdT,
                                                  const float* __restrict__ bdec,
                                                  float* __restrict__ recon) {
    const int wave = threadIdx.x >> 6, lane = threadIdx.x & 63;
    const int r = blockIdx.x * 4 + wave;

    float lv = 0.f; int li = 0;
    if (lane < K_SEL) {
        lv = vals[(size_t)r * K_SEL + lane];
        li = idxs[(size_t)r * K_SEL + lane];
    }
    float acc[10];
#pragma unroll
    for (int e = 0; e < 10; ++e) acc[e] = bdec[lane + e * 64];

#pragma unroll 4
    for (int k = 0; k < K_SEL; ++k) {
        float vkv = __shfl(lv, k);
        int   j   = __shfl(li, k);
        const float* w = WdT + (size_t)j * D_IN + lane;
#pragma unroll
        for (int e = 0; e < 10; ++e) acc[e] = fmaf(vkv, w[e * 64], acc[e]);
    }
    float* out = recon + (size_t)r * D_IN + lane;
#pragma unroll
    for (int e = 0; e < 10; ++e) out[e * 64] = acc[e];
}

extern "C" void kernel_launch(void* const* d_in, const int* in_sizes, int n_in,
                              void* d_out, int out_size, void* d_ws, size_t ws_size,
                              hipStream_t stream) {
    const float* x     = (const float*)d_in[0];
    const float* W_enc = (const float*)d_in[1];
    const float* b_enc = (const float*)d_in[2];
    const float* W_dec = (const float*)d_in[3];
    const float* b_dec = (const float*)d_in[4];

    float* recon  = (float*)d_out;                                  // [B][640]
    float* sparse = (float*)d_out + (size_t)B_ROWS * D_IN;          // [B][2560]

    char* ws = (char*)d_ws;
    size_t off = 0;
    float* WdT  = (float*)(ws + off); off += (size_t)D_LAT * D_IN * 4;     // 6.55 MB
    float* vals = (float*)(ws + off); off += (size_t)B_ROWS * K_SEL * 4;   // 8.4 MB
    int*   idxs = (int*)  (ws + off);                                      // 8.4 MB

    hipLaunchKernelGGL(transpose_wdec, dim3(D_LAT / 32, D_IN / 32), dim3(256), 0, stream,
                       W_dec, WdT);
    hipLaunchKernelGGL(enc_gemm, dim3(D_LAT / BN, B_ROWS / BM), dim3(256), 0, stream,
                       x, W_enc, b_enc, sparse);
    hipLaunchKernelGGL(topk32, dim3(B_ROWS / 4), dim3(256), 0, stream,
                       sparse, vals, idxs);
    hipLaunchKernelGGL(dec_kernel, dim3(B_ROWS / 4), dim3(256), 0, stream,
                       vals, idxs, WdT, b_dec, recon);
}

// Round 10
// 3724.891 us; speedup vs baseline: 1.2072x; 1.2072x over previous
//
#include <hip/hip_runtime.h>
#include <cstdint>

#define B_ROWS 65536
#define D_IN   640
#define D_LAT  2560
#define K_SEL  32
#define NCAND  48
#define EPL    40   // 2560/64 elements per lane in wave topk
// np-exact K-panel boundaries (OpenBLAS SKYLAKEX Q=192): 192+192+128+128
#define P1 192
#define P2 384
#define P3 512

typedef __attribute__((ext_vector_type(8))) short short8;
typedef __attribute__((ext_vector_type(4))) float f32x4;

static __device__ __forceinline__ ushort f2bf(float f) {
    uint32_t u = __float_as_uint(f);
    u += 0x7fffu + ((u >> 16) & 1u);   // round-to-nearest-even
    return (ushort)(u >> 16);
}

// ---------------- W_enc fp32 -> bf16 copy ----------------------------------------
__global__ __launch_bounds__(256) void cvt_wenc(const float* __restrict__ We,
                                                ushort* __restrict__ WeB) {
    const size_t i = ((size_t)blockIdx.x * 256 + threadIdx.x) * 4;
    float4 v = *(const float4*)(We + i);
    ushort4 o;
    o.x = f2bf(v.x); o.y = f2bf(v.y); o.z = f2bf(v.z); o.w = f2bf(v.w);
    *(ushort4*)(WeB + i) = o;
}

// ---------------- W_dec transpose: [640][2560] -> WdT [2560][640] ----------------
__global__ __launch_bounds__(256) void transpose_wdec(const float* __restrict__ Wd,
                                                      float* __restrict__ WdT) {
    __shared__ float t[32][33];
    const int j0 = blockIdx.x * 32;
    const int i0 = blockIdx.y * 32;
    const int tx = threadIdx.x & 31, ty = threadIdx.x >> 5;
#pragma unroll
    for (int q = 0; q < 4; ++q)
        t[ty + 8 * q][tx] = Wd[(size_t)(i0 + ty + 8 * q) * D_LAT + j0 + tx];
    __syncthreads();
#pragma unroll
    for (int q = 0; q < 4; ++q)
        WdT[(size_t)(j0 + ty + 8 * q) * D_IN + i0 + tx] = t[tx][ty + 8 * q];
}

// ---------------- bf16 MFMA filter GEMM: approx latents --------------------------
// C[M][N] = A[M][K] (fp32->bf16) x WeB[N][K]^T + bias. 128x128 tile, BK=32.
// Accuracy: input-rounding only (sigma ~3e-3) -- candidate filter, not exact.
__global__ __launch_bounds__(256, 2) void enc_mfma(const float* __restrict__ A,
                                                   const ushort* __restrict__ Wb,
                                                   const float* __restrict__ bias,
                                                   float* __restrict__ C) {
    __shared__ ushort Al[128][40];   // pad 32->40: conflict-light ds_read_b128
    __shared__ ushort Bl[128][40];
    const int tid = threadIdx.x;
    const int n0 = blockIdx.x * 128;
    const int m0 = blockIdx.y * 128;
    const int srow = tid >> 1, shalf = tid & 1;   // stager: row, k-half(16)
    const float*  Ap = A  + (size_t)(m0 + srow) * D_IN + shalf * 16;
    const ushort* Bp = Wb + (size_t)(n0 + srow) * D_IN + shalf * 16;

    const int w = tid >> 6, l = tid & 63;
    const int wm = w >> 1, wn = w & 1;            // 2x2 waves over 128x128
    const int fr = l & 15, ko = l >> 4;           // frag row/col, k-octet

    f32x4 acc[4][4];
#pragma unroll
    for (int i = 0; i < 4; ++i)
#pragma unroll
        for (int j = 0; j < 4; ++j) acc[i][j] = (f32x4)0.0f;

    float4 a0, a1, a2, a3; uint4 b0, b1;
#define LOADT(KT)                                                    \
    {                                                                \
        const float* ap = Ap + (KT) * 32;                            \
        a0 = *(const float4*)(ap);                                   \
        a1 = *(const float4*)(ap + 4);                               \
        a2 = *(const float4*)(ap + 8);                               \
        a3 = *(const float4*)(ap + 12);                              \
        const uint* bp = (const uint*)(Bp + (KT) * 32);              \
        b0 = *(const uint4*)(bp);                                    \
        b1 = *(const uint4*)(bp + 4);                                \
    }

    LOADT(0);
    const int NT = D_IN / 32;   // 20
    for (int kt = 0; kt < NT; ++kt) {
        union { ushort u[8]; short8 v; } p0, p1;
        p0.u[0] = f2bf(a0.x); p0.u[1] = f2bf(a0.y); p0.u[2] = f2bf(a0.z); p0.u[3] = f2bf(a0.w);
        p0.u[4] = f2bf(a1.x); p0.u[5] = f2bf(a1.y); p0.u[6] = f2bf(a1.z); p0.u[7] = f2bf(a1.w);
        p1.u[0] = f2bf(a2.x); p1.u[1] = f2bf(a2.y); p1.u[2] = f2bf(a2.z); p1.u[3] = f2bf(a2.w);
        p1.u[4] = f2bf(a3.x); p1.u[5] = f2bf(a3.y); p1.u[6] = f2bf(a3.z); p1.u[7] = f2bf(a3.w);
        *(short8*)&Al[srow][shalf * 16]     = p0.v;
        *(short8*)&Al[srow][shalf * 16 + 8] = p1.v;
        *(uint4*)&Bl[srow][shalf * 16]      = b0;
        *(uint4*)&Bl[srow][shalf * 16 + 8]  = b1;
        __syncthreads();
        if (kt + 1 < NT) LOADT(kt + 1);

        short8 af[4], bf[4];
#pragma unroll
        for (int fm = 0; fm < 4; ++fm)
            af[fm] = *(const short8*)&Al[wm * 64 + fm * 16 + fr][ko * 8];
#pragma unroll
        for (int fn = 0; fn < 4; ++fn)
            bf[fn] = *(const short8*)&Bl[wn * 64 + fn * 16 + fr][ko * 8];
#pragma unroll
        for (int fm = 0; fm < 4; ++fm)
#pragma unroll
            for (int fn = 0; fn < 4; ++fn)
                acc[fm][fn] = __builtin_amdgcn_mfma_f32_16x16x32_bf16(
                    af[fm], bf[fn], acc[fm][fn], 0, 0, 0);
        __syncthreads();
    }
#undef LOADT

#pragma unroll
    for (int fn = 0; fn < 4; ++fn) {
        const int col = n0 + wn * 64 + fn * 16 + fr;
        const float bb = bias[col];
#pragma unroll
        for (int fm = 0; fm < 4; ++fm) {
#pragma unroll
            for (int j = 0; j < 4; ++j) {
                const int row = m0 + wm * 64 + fm * 16 + ko * 4 + j;
                C[(size_t)row * D_LAT + col] = acc[fm][fn][j] + bb;
            }
        }
    }
}

// ---------------- Candidate top-NCAND per row (approx; set only matters) ---------
__global__ __launch_bounds__(256) void topk_cand(const float* __restrict__ lat,
                                                 int* __restrict__ cidx) {
    const int wv = threadIdx.x >> 6, lane = threadIdx.x & 63;
    const int r = blockIdx.x * 4 + wv;
    const float* row = lat + (size_t)r * D_LAT;

    float v[EPL];
#pragma unroll
    for (int e = 0; e < EPL; ++e) v[e] = row[e * 64 + lane];

    const float NEGINF = -__builtin_inff();
    uint64_t mask = 0;
    float lm = NEGINF; int li = 0x7fffffff;
#pragma unroll
    for (int e = 0; e < EPL; ++e)
        if (v[e] > lm) { lm = v[e]; li = e * 64 + lane; }

    for (int t = 0; t < NCAND; ++t) {
        float bv = lm; int bi = li;
#pragma unroll
        for (int off = 1; off < 64; off <<= 1) {
            float ov = __shfl_xor(bv, off);
            int   oi = __shfl_xor(bi, off);
            if (ov > bv || (ov == bv && oi < bi)) { bv = ov; bi = oi; }
        }
        if (lane == 0) cidx[(size_t)r * NCAND + t] = bi;
        if (li == bi) {
            mask |= 1ull << (bi >> 6);
            lm = NEGINF; li = 0x7fffffff;
#pragma unroll
            for (int e = 0; e < EPL; ++e)
                if (!((mask >> e) & 1) && v[e] > lm) { lm = v[e]; li = e * 64 + lane; }
        }
    }
}

// ---------------- Exact refine: np-bit-exact 4-panel chains on 48 candidates -----
// lane c recomputes candidate c's latent with the EXACT R9 semantics:
// 4 fp32 fmaf chains (k ascending within panel), ((a0+a1)+a2)+a3 + bias.
// Then top-32 among exact values, ties -> lower latent index.
__global__ __launch_bounds__(256) void refine_exact(const float* __restrict__ x,
                                                    const float* __restrict__ We,
                                                    const float* __restrict__ be,
                                                    const int* __restrict__ cidx,
                                                    float* __restrict__ sparse,
                                                    float* __restrict__ vals,
                                                    int* __restrict__ idxs) {
    const int tid = threadIdx.x;
    const int wv = tid >> 6, lane = tid & 63;
    const int r = blockIdx.x * 4 + wv;

    __shared__ float xs[4][D_IN];
    const float* xr = x + (size_t)r * D_IN;
#pragma unroll
    for (int q = 0; q < 10; ++q) xs[wv][lane + q * 64] = xr[lane + q * 64];
    // same-wave LDS produce->consume: lockstep, compiler inserts lgkmcnt

    const int j = (lane < NCAND) ? cidx[(size_t)r * NCAND + lane] : 0;
    const float* wp = We + (size_t)j * D_IN;

    float a0 = 0.f, a1 = 0.f, a2 = 0.f, a3 = 0.f;
#define CHAIN(ACC, KB, KE)                                           \
    for (int k = (KB); k < (KE); k += 4) {                           \
        const float4 wq = *(const float4*)(wp + k);                  \
        const float4 xq = *(const float4*)&xs[wv][k];                \
        ACC = fmaf(wq.x, xq.x, ACC);                                 \
        ACC = fmaf(wq.y, xq.y, ACC);                                 \
        ACC = fmaf(wq.z, xq.z, ACC);                                 \
        ACC = fmaf(wq.w, xq.w, ACC);                                 \
    }
    CHAIN(a0, 0,  P1)
    CHAIN(a1, P1, P2)
    CHAIN(a2, P2, P3)
    CHAIN(a3, P3, D_IN)
#undef CHAIN
    const float val = (((a0 + a1) + a2) + a3) + be[j];

    const float NEGINF = -__builtin_inff();
    float mv = (lane < NCAND) ? val : NEGINF;
    int   mi = (lane < NCAND) ? j : 0x7fffffff;
    bool  selected = false;
    for (int t = 0; t < K_SEL; ++t) {
        float bv = mv; int bi = mi;
#pragma unroll
        for (int off = 1; off < 64; off <<= 1) {
            float ov = __shfl_xor(bv, off);
            int   oi = __shfl_xor(bi, off);
            if (ov > bv || (ov == bv && oi < bi)) { bv = ov; bi = oi; }
        }
        if (lane == 0) {
            vals[(size_t)r * K_SEL + t] = bv;
            idxs[(size_t)r * K_SEL + t] = bi;
        }
        if (bi == mi) {           // winner lane (candidate j's unique)
            selected = true;
            mv = NEGINF; mi = 0x7fffffff;
        }
    }

    // zero the block's 4 sparse rows, then scatter exact winners
    __syncthreads();
    float4 z; z.x = z.y = z.z = z.w = 0.f;
    float4* srow4 = (float4*)(sparse + (size_t)blockIdx.x * 4 * D_LAT);
    for (int p = tid; p < 4 * D_LAT / 4; p += 256) srow4[p] = z;
    __syncthreads();
    if (lane < NCAND && selected) sparse[(size_t)r * D_LAT + j] = val;
}

// ---------------- Decoder: recon[r] = sum_k vals[r][k] * WdT[idx[r][k]][:] + b_dec
__global__ __launch_bounds__(256) void dec_kernel(const float* __restrict__ vals,
                                                  const int* __restrict__ idxs,
                                                  const float* __restrict__ WdT,
                                                  const float* __restrict__ bdec,
                                                  float* __restrict__ recon) {
    const int wave = threadIdx.x >> 6, lane = threadIdx.x & 63;
    const int r = blockIdx.x * 4 + wave;

    float lv = 0.f; int li = 0;
    if (lane < K_SEL) {
        lv = vals[(size_t)r * K_SEL + lane];
        li = idxs[(size_t)r * K_SEL + lane];
    }
    float acc[10];
#pragma unroll
    for (int e = 0; e < 10; ++e) acc[e] = bdec[lane + e * 64];

#pragma unroll 4
    for (int k = 0; k < K_SEL; ++k) {
        float vkv = __shfl(lv, k);
        int   jj  = __shfl(li, k);
        const float* wr = WdT + (size_t)jj * D_IN + lane;
#pragma unroll
        for (int e = 0; e < 10; ++e) acc[e] = fmaf(vkv, wr[e * 64], acc[e]);
    }
    float* out = recon + (size_t)r * D_IN + lane;
#pragma unroll
    for (int e = 0; e < 10; ++e) out[e * 64] = acc[e];
}

extern "C" void kernel_launch(void* const* d_in, const int* in_sizes, int n_in,
                              void* d_out, int out_size, void* d_ws, size_t ws_size,
                              hipStream_t stream) {
    const float* x     = (const float*)d_in[0];
    const float* W_enc = (const float*)d_in[1];
    const float* b_enc = (const float*)d_in[2];
    const float* W_dec = (const float*)d_in[3];
    const float* b_dec = (const float*)d_in[4];

    float* recon  = (float*)d_out;                                  // [B][640]
    float* sparse = (float*)d_out + (size_t)B_ROWS * D_IN;          // [B][2560] (scratch then final)

    char* ws = (char*)d_ws;
    size_t off = 0;
    float*  WdT  = (float*) (ws + off); off += (size_t)D_LAT * D_IN * 4;    // 6.55 MB
    ushort* WeB  = (ushort*)(ws + off); off += (size_t)D_LAT * D_IN * 2;    // 3.28 MB
    int*    cidx = (int*)   (ws + off); off += (size_t)B_ROWS * NCAND * 4;  // 12.6 MB
    float*  vals = (float*) (ws + off); off += (size_t)B_ROWS * K_SEL * 4;  // 8.4 MB
    int*    idxs = (int*)   (ws + off);                                     // 8.4 MB

    hipLaunchKernelGGL(cvt_wenc, dim3(D_LAT * D_IN / (256 * 4)), dim3(256), 0, stream,
                       W_enc, WeB);
    hipLaunchKernelGGL(transpose_wdec, dim3(D_LAT / 32, D_IN / 32), dim3(256), 0, stream,
                       W_dec, WdT);
    hipLaunchKernelGGL(enc_mfma, dim3(D_LAT / 128, B_ROWS / 128), dim3(256), 0, stream,
                       x, WeB, b_enc, sparse);
    hipLaunchKernelGGL(topk_cand, dim3(B_ROWS / 4), dim3(256), 0, stream,
                       sparse, cidx);
    hipLaunchKernelGGL(refine_exact, dim3(B_ROWS / 4), dim3(256), 0, stream,
                       x, W_enc, b_enc, cidx, sparse, vals, idxs);
    hipLaunchKernelGGL(dec_kernel, dim3(B_ROWS / 4), dim3(256), 0, stream,
                       vals, idxs, WdT, b_dec, recon);
}